// Round 1
// baseline (599.302 us; speedup 1.0000x reference)
//
#include <hip/hip_runtime.h>
#include <hip/hip_bf16.h>
#include <cstdint>
#include <cstddef>

// ---------- types ----------
typedef __attribute__((ext_vector_type(8)))  short  s16x8;
typedef __attribute__((ext_vector_type(4)))  float  fp32x4;
typedef __attribute__((ext_vector_type(16))) float  fp32x16;
typedef __attribute__((ext_vector_type(4)))  unsigned short u16x4;

static __device__ __forceinline__ float bf2f(unsigned short u) {
    union { unsigned int i; float f; } v; v.i = ((unsigned int)u) << 16; return v.f;
}
static __device__ __forceinline__ unsigned short f2bf(float f) {
    __hip_bfloat16 h = __float2bfloat16(f);   // RNE
    return __builtin_bit_cast(unsigned short, h);
}

static __device__ __forceinline__ fp32x16 mfma32(s16x8 a, s16x8 b, fp32x16 c) {
    return __builtin_amdgcn_mfma_f32_32x32x16_bf16(a, b, c, 0, 0, 0);
}
static __device__ __forceinline__ fp32x4 mfma16(s16x8 a, s16x8 b, fp32x4 c) {
    return __builtin_amdgcn_mfma_f32_16x16x32_bf16(a, b, c, 0, 0, 0);
}

static __device__ __forceinline__ float wave_sum(float v) {
#pragma unroll
    for (int off = 32; off > 0; off >>= 1) v += __shfl_xor(v, off, 64);
    return v;
}

// ---------- constants ----------
// tokens = 2*16*64*64 = 131072, C=256, windows: 4096 of N=32, heads=8, d=32
#define NTOK   131072
#define CDIM   256

// ---------- prep: weight transposes (fp32 -> bf16, [N][K]) + rel-pos bias table ----------
__global__ void prep_kernel(const float* __restrict__ qkv_w, const float* __restrict__ proj_w,
                            const float* __restrict__ w1,    const float* __restrict__ w2,
                            const float* __restrict__ rel,
                            unsigned short* __restrict__ qkvT, unsigned short* __restrict__ projT,
                            unsigned short* __restrict__ w1T,  unsigned short* __restrict__ w2T,
                            float* __restrict__ btab) {
    int id = blockIdx.x * 256 + threadIdx.x;
    if (id < 196608) {                       // qkv_w [256][768] -> [768][256]
        int n = id >> 8, k = id & 255;
        qkvT[id] = f2bf(qkv_w[k * 768 + n]);
    } else if (id < 262144) {                // proj_w [256][256] -> [256][256]^T
        int e = id - 196608; int n = e >> 8, k = e & 255;
        projT[e] = f2bf(proj_w[k * 256 + n]);
    } else if (id < 524288) {                // mlp_w1 [256][1024] -> [1024][256]
        int e = id - 262144; int n = e >> 8, k = e & 255;
        w1T[e] = f2bf(w1[k * 1024 + n]);
    } else if (id < 786432) {                // mlp_w2 [1024][256] -> [256][1024]
        int e = id - 524288; int n = e >> 10, k = e & 1023;
        w2T[e] = f2bf(w2[k * 256 + n]);
    } else {                                 // bias table [8][32][32]
        int e = id - 786432;
        int h = e >> 10, rem = e & 1023, n = rem >> 5, m = rem & 31;
        int tn = n >> 4, hn = (n >> 2) & 3, wn = n & 3;
        int tm = m >> 4, hm = (m >> 2) & 3, wm = m & 3;
        int ridx = (tn - tm + 1) * 49 + (hn - hm + 3) * 7 + (wn - wm + 3);
        btab[e] = rel[ridx * 8 + h];
    }
}

// ---------- LayerNorm: MODE 0 = LN1 + roll(-1,-2,-2) + window partition (gather)
//                        MODE 1 = LN2 identity order ----------
template <int MODE>
__global__ __launch_bounds__(256) void ln_kernel(const float* __restrict__ in,
                                                 const float* __restrict__ w,
                                                 const float* __restrict__ b,
                                                 unsigned short* __restrict__ out) {
    int tid = threadIdx.x, lane = tid & 63, wid = tid >> 6;
    long r = (long)blockIdx.x * 4 + wid;
    long src;
    if (MODE == 0) {
        int n = (int)(r & 31); int win = (int)(r >> 5);
        int b_ = win >> 11, tw = (win >> 8) & 7, hw = (win >> 4) & 15, ww = win & 15;
        int ti = n >> 4, hi = (n >> 2) & 3, wi = n & 3;
        int t = tw * 2 + ti, hh = hw * 4 + hi, wv = ww * 4 + wi;
        int ts = (t + 1) & 15, hs = (hh + 2) & 63, wsd = (wv + 2) & 63;
        src = ((long)((b_ * 16 + ts) * 64 + hs)) * 64 + wsd;
    } else {
        src = r;
    }
    float4 v = *(const float4*)&in[src * CDIM + lane * 4];
    float vv[4] = {v.x, v.y, v.z, v.w};
    float s = vv[0] + vv[1] + vv[2] + vv[3];
    s = wave_sum(s);
    float mean = s * (1.0f / 256.0f);
    float q = vv[0]*vv[0] + vv[1]*vv[1] + vv[2]*vv[2] + vv[3]*vv[3];
    q = wave_sum(q);
    float var = q * (1.0f / 256.0f) - mean * mean;
    float rstd = rsqrtf(var + 1e-5f);
    int c0 = lane * 4;
    u16x4 o;
#pragma unroll
    for (int j = 0; j < 4; ++j)
        o[j] = f2bf((vv[j] - mean) * rstd * w[c0 + j] + b[c0 + j]);
    *(u16x4*)&out[r * CDIM + c0] = o;
}

// ---------- GEMM: C[M,N] = epi(A[M,K](bf16) @ Bt[N,K]^T(bf16) + bias) ----------
// 128x128 tile, BK=64, 4 waves (2x2 of 64x64), double-buffered LDS, XOR chunk swizzle.
// EPI: 0 = bf16 store (stride NS)        1 = proj: window-reverse scatter + residual -> fp32
//      2 = GELU -> bf16 (stride NS)       3 = += into fp32 out (stride NS)
template <int K, int EPI, int NS>
__global__ __launch_bounds__(256, 2) void gemm_k(const unsigned short* __restrict__ A,
                                                 const unsigned short* __restrict__ Bt,
                                                 const float* __restrict__ bias,
                                                 float* __restrict__ outf,
                                                 unsigned short* __restrict__ outb,
                                                 const float* __restrict__ resid) {
    __shared__ unsigned short smem[32768];   // 2 bufs x (A 8192 + B 8192) ushorts = 64 KiB
    const int tid = threadIdx.x;
    const int lane = tid & 63, wid = tid >> 6;
    const int m0 = blockIdx.y * 128, n0 = blockIdx.x * 128;
    const int wm = (wid >> 1) * 64, wn = (wid & 1) * 64;
    constexpr int NK = K / 64;

    fp32x4 acc[4][4] = {};

    auto stage = [&](int kt, int buf) {
#pragma unroll
        for (int i = 0; i < 4; ++i) {
            int L = i * 256 + tid;
            int r = L >> 3, c = L & 7;
            int sw = c ^ (r & 7);
            const unsigned short* ga = A + (size_t)(m0 + r) * K + kt * 64 + sw * 8;
            __builtin_amdgcn_global_load_lds(
                (const __attribute__((address_space(1))) void*)ga,
                (__attribute__((address_space(3))) void*)(smem + buf * 16384 + L * 8),
                16, 0, 0);
            const unsigned short* gb = Bt + (size_t)(n0 + r) * K + kt * 64 + sw * 8;
            __builtin_amdgcn_global_load_lds(
                (const __attribute__((address_space(1))) void*)gb,
                (__attribute__((address_space(3))) void*)(smem + buf * 16384 + 8192 + L * 8),
                16, 0, 0);
        }
    };

    stage(0, 0);
    for (int kt = 0; kt < NK; ++kt) {
        __syncthreads();
        if (kt + 1 < NK) stage(kt + 1, (kt + 1) & 1);
        const unsigned short* As = smem + (kt & 1) * 16384;
        const unsigned short* Bs = As + 8192;
#pragma unroll
        for (int ks = 0; ks < 2; ++ks) {
            s16x8 a[4], b[4];
#pragma unroll
            for (int m = 0; m < 4; ++m) {
                int row = wm + m * 16 + (lane & 15);
                int ch = (ks * 4 + (lane >> 4)) ^ (row & 7);
                a[m] = *(const s16x8*)(As + row * 64 + ch * 8);
            }
#pragma unroll
            for (int n = 0; n < 4; ++n) {
                int row = wn + n * 16 + (lane & 15);
                int ch = (ks * 4 + (lane >> 4)) ^ (row & 7);
                b[n] = *(const s16x8*)(Bs + row * 64 + ch * 8);
            }
#pragma unroll
            for (int m = 0; m < 4; ++m)
#pragma unroll
                for (int n = 0; n < 4; ++n)
                    acc[m][n] = mfma16(a[m], b[n], acc[m][n]);
        }
    }

    // epilogue
    float bv[4];
#pragma unroll
    for (int n = 0; n < 4; ++n) bv[n] = bias[n0 + wn + n * 16 + (lane & 15)];

#pragma unroll
    for (int m = 0; m < 4; ++m) {
#pragma unroll
        for (int rg = 0; rg < 4; ++rg) {
            int row_t = wm + m * 16 + ((lane >> 4) << 2) + rg;
            size_t gr = (size_t)m0 + row_t;
            size_t dst = 0;
            if (EPI == 1) {
                int win = (int)(gr >> 5), n_ = (int)(gr & 31);
                int b_ = win >> 11, tw = (win >> 8) & 7, hw = (win >> 4) & 15, ww = win & 15;
                int ti = n_ >> 4, hi = (n_ >> 2) & 3, wi = n_ & 3;
                int t = tw * 2 + ti, hh = hw * 4 + hi, wv = ww * 4 + wi;
                int ts = (t + 1) & 15, hs = (hh + 2) & 63, wsd = (wv + 2) & 63;
                dst = ((size_t)((b_ * 16 + ts) * 64 + hs)) * 64 + wsd;
            }
#pragma unroll
            for (int n = 0; n < 4; ++n) {
                int gc = n0 + wn + n * 16 + (lane & 15);
                float v = acc[m][n][rg] + bv[n];
                if (EPI == 0) {
                    outb[gr * NS + gc] = f2bf(v);
                } else if (EPI == 1) {
                    outf[dst * CDIM + gc] = resid[dst * CDIM + gc] + v;
                } else if (EPI == 2) {
                    float g = 0.5f * v * (1.0f + erff(v * 0.70710678118654752f));
                    outb[gr * NS + gc] = f2bf(g);
                } else {
                    outf[gr * NS + gc] += v;
                }
            }
        }
    }
}

// ---------- windowed attention: one wave per (window, head) ----------
__global__ __launch_bounds__(256) void attn_kernel(const unsigned short* __restrict__ qkv,
                                                   const float* __restrict__ btab,
                                                   unsigned short* __restrict__ obuf) {
    __shared__ unsigned short sP[4][1280];    // 32 x 40 (pad) bf16 per wave
    __shared__ unsigned short sVt[4][1280];
    int tid = threadIdx.x, lane = tid & 63, wid = tid >> 6;
    int task = blockIdx.x * 4 + wid;          // 32768 tasks
    int win = task >> 3, hh = task & 7;
    const unsigned short* base = qkv + (size_t)win * 32 * 768 + hh * 32;
    int q = lane & 31, h = lane >> 5;

    // V -> LDS transposed (Vt[d][key])
    s16x8 v0 = *(const s16x8*)(base + 512 + q * 768 + h * 16);
    s16x8 v1 = *(const s16x8*)(base + 512 + q * 768 + h * 16 + 8);
#pragma unroll
    for (int j = 0; j < 8; ++j) {
        sVt[wid][(h * 16 + j) * 40 + q]     = (unsigned short)v0[j];
        sVt[wid][(h * 16 + 8 + j) * 40 + q] = (unsigned short)v1[j];
    }

    // S = Q K^T  (A: row=q, k=d ; B: col=key, k=d — both contiguous loads)
    s16x8 aq0 = *(const s16x8*)(base + q * 768 + h * 8);
    s16x8 aq1 = *(const s16x8*)(base + q * 768 + 16 + h * 8);
    s16x8 bk0 = *(const s16x8*)(base + 256 + q * 768 + h * 8);
    s16x8 bk1 = *(const s16x8*)(base + 256 + q * 768 + 16 + h * 8);
    fp32x16 S = {0.0f};
    S = mfma32(aq0, bk0, S);
    S = mfma32(aq1, bk1, S);

    const float scale = 0.17677669529663687f;   // 1/sqrt(32)
    float pr[16];
#pragma unroll
    for (int r = 0; r < 16; ++r) {
        int row = (r & 3) + 8 * (r >> 2) + 4 * h;
        float bvv = btab[(hh * 32 + row) * 32 + q];
        pr[r] = S[r] * scale + bvv;
    }
    // softmax per row: each reg is one row, cols live across 32 lanes of this half
#pragma unroll
    for (int r = 0; r < 16; ++r) {
        float mx = pr[r];
#pragma unroll
        for (int off = 16; off > 0; off >>= 1) mx = fmaxf(mx, __shfl_xor(mx, off, 64));
        float e = __expf(pr[r] - mx);
        float sm = e;
#pragma unroll
        for (int off = 16; off > 0; off >>= 1) sm += __shfl_xor(sm, off, 64);
        pr[r] = e * __builtin_amdgcn_rcpf(sm);
    }
#pragma unroll
    for (int r = 0; r < 16; ++r) {
        int row = (r & 3) + 8 * (r >> 2) + 4 * h;
        sP[wid][row * 40 + q] = f2bf(pr[r]);
    }
    __syncthreads();

    // O = P V   (A: row=q(query), k=key from sP ; B: col=d, k=key from sVt)
    s16x8 pa0 = *(const s16x8*)&sP[wid][q * 40 + h * 8];
    s16x8 pa1 = *(const s16x8*)&sP[wid][q * 40 + 16 + h * 8];
    s16x8 vb0 = *(const s16x8*)&sVt[wid][q * 40 + h * 8];
    s16x8 vb1 = *(const s16x8*)&sVt[wid][q * 40 + 16 + h * 8];
    fp32x16 O = {0.0f};
    O = mfma32(pa0, vb0, O);
    O = mfma32(pa1, vb1, O);
#pragma unroll
    for (int r = 0; r < 16; ++r) {
        int row = (r & 3) + 8 * (r >> 2) + 4 * h;
        obuf[((size_t)win * 32 + row) * 256 + hh * 32 + q] = f2bf(O[r]);
    }
}

// ---------- launcher ----------
extern "C" void kernel_launch(void* const* d_in, const int* in_sizes, int n_in,
                              void* d_out, int out_size, void* d_ws, size_t ws_size,
                              hipStream_t stream) {
    const float* x      = (const float*)d_in[0];
    const float* n1w    = (const float*)d_in[1];
    const float* n1b    = (const float*)d_in[2];
    const float* qkv_w  = (const float*)d_in[3];
    const float* qkv_b  = (const float*)d_in[4];
    const float* proj_w = (const float*)d_in[5];
    const float* proj_b = (const float*)d_in[6];
    const float* rel    = (const float*)d_in[7];
    const float* n2w    = (const float*)d_in[8];
    const float* n2b    = (const float*)d_in[9];
    const float* w1     = (const float*)d_in[10];
    const float* b1     = (const float*)d_in[11];
    const float* w2     = (const float*)d_in[12];
    const float* b2     = (const float*)d_in[13];
    float* out = (float*)d_out;

    char* ws = (char*)d_ws;
    unsigned short* hwin = (unsigned short*)ws;                       // 67,108,864 B (hwin/obuf/a2)
    unsigned short* big  = (unsigned short*)(ws + 67108864);          // 268,435,456 B (qkv/hidden)
    char* wreg = ws + 67108864 + 268435456;
    unsigned short* qkvT  = (unsigned short*)(wreg);
    unsigned short* projT = (unsigned short*)(wreg + 393216);
    unsigned short* w1T   = (unsigned short*)(wreg + 524288);
    unsigned short* w2T   = (unsigned short*)(wreg + 1048576);
    float*          btab  = (float*)(wreg + 1572864);

    prep_kernel<<<3104, 256, 0, stream>>>(qkv_w, proj_w, w1, w2, rel, qkvT, projT, w1T, w2T, btab);

    ln_kernel<0><<<NTOK / 4, 256, 0, stream>>>(x, n1w, n1b, hwin);

    // qkv = hwin @ qkvT^T + qkv_b -> bf16 [NTOK][768]
    gemm_k<256, 0, 768><<<dim3(6, 1024), 256, 0, stream>>>(hwin, qkvT, qkv_b, nullptr, big, nullptr);

    attn_kernel<<<8192, 256, 0, stream>>>(big, btab, hwin);           // obuf -> hwin region

    // proj + window-reverse + roll + residual -> d_out (x2)
    gemm_k<256, 1, 256><<<dim3(2, 1024), 256, 0, stream>>>(hwin, projT, proj_b, out, nullptr, x);

    ln_kernel<1><<<NTOK / 4, 256, 0, stream>>>(out, n2w, n2b, hwin);  // a2 -> hwin region

    // hidden = gelu(a2 @ w1T^T + b1) -> bf16 [NTOK][1024]
    gemm_k<256, 2, 1024><<<dim3(8, 1024), 256, 0, stream>>>(hwin, w1T, b1, nullptr, big, nullptr);

    // d_out += hidden @ w2T^T + b2
    gemm_k<1024, 3, 256><<<dim3(2, 1024), 256, 0, stream>>>(big, w2T, b2, out, nullptr, nullptr);
}

// Round 2
// 597.797 us; speedup vs baseline: 1.0025x; 1.0025x over previous
//
#include <hip/hip_runtime.h>
#include <hip/hip_bf16.h>
#include <cstdint>
#include <cstddef>

// ---------- types ----------
typedef __attribute__((ext_vector_type(8)))  short  s16x8;
typedef __attribute__((ext_vector_type(4)))  float  fp32x4;
typedef __attribute__((ext_vector_type(16))) float  fp32x16;
typedef __attribute__((ext_vector_type(4)))  unsigned short u16x4;

static __device__ __forceinline__ float bf2f(unsigned short u) {
    union { unsigned int i; float f; } v; v.i = ((unsigned int)u) << 16; return v.f;
}
static __device__ __forceinline__ unsigned short f2bf(float f) {
    __hip_bfloat16 h = __float2bfloat16(f);   // RNE
    return __builtin_bit_cast(unsigned short, h);
}

static __device__ __forceinline__ fp32x16 mfma32(s16x8 a, s16x8 b, fp32x16 c) {
    return __builtin_amdgcn_mfma_f32_32x32x16_bf16(a, b, c, 0, 0, 0);
}
static __device__ __forceinline__ fp32x4 mfma16(s16x8 a, s16x8 b, fp32x4 c) {
    return __builtin_amdgcn_mfma_f32_16x16x32_bf16(a, b, c, 0, 0, 0);
}

static __device__ __forceinline__ float wave_sum(float v) {
#pragma unroll
    for (int off = 32; off > 0; off >>= 1) v += __shfl_xor(v, off, 64);
    return v;
}

// ---------- constants ----------
#define NTOK   131072
#define CDIM   256

// ---------- prep: weight transposes (fp32 -> bf16, [N][K]) + rel-pos bias table ----------
__global__ void prep_kernel(const float* __restrict__ qkv_w, const float* __restrict__ proj_w,
                            const float* __restrict__ w1,    const float* __restrict__ w2,
                            const float* __restrict__ rel,
                            unsigned short* __restrict__ qkvT, unsigned short* __restrict__ projT,
                            unsigned short* __restrict__ w1T,  unsigned short* __restrict__ w2T,
                            float* __restrict__ btab) {
    int id = blockIdx.x * 256 + threadIdx.x;
    if (id < 196608) {                       // qkv_w [256][768] -> [768][256]
        int n = id >> 8, k = id & 255;
        qkvT[id] = f2bf(qkv_w[k * 768 + n]);
    } else if (id < 262144) {                // proj_w [256][256] -> [256][256]^T
        int e = id - 196608; int n = e >> 8, k = e & 255;
        projT[e] = f2bf(proj_w[k * 256 + n]);
    } else if (id < 524288) {                // mlp_w1 [256][1024] -> [1024][256]
        int e = id - 262144; int n = e >> 8, k = e & 255;
        w1T[e] = f2bf(w1[k * 1024 + n]);
    } else if (id < 786432) {                // mlp_w2 [1024][256] -> [256][1024]
        int e = id - 524288; int n = e >> 10, k = e & 1023;
        w2T[e] = f2bf(w2[k * 256 + n]);
    } else {                                 // bias table [8][32][32]
        int e = id - 786432;
        int h = e >> 10, rem = e & 1023, n = rem >> 5, m = rem & 31;
        int tn = n >> 4, hn = (n >> 2) & 3, wn = n & 3;
        int tm = m >> 4, hm = (m >> 2) & 3, wm = m & 3;
        int ridx = (tn - tm + 1) * 49 + (hn - hm + 3) * 7 + (wn - wm + 3);
        btab[e] = rel[ridx * 8 + h];
    }
}

// ---------- LayerNorm: MODE 0 = LN1 + roll + window partition; MODE 1 = LN2 ----------
template <int MODE>
__global__ __launch_bounds__(256) void ln_kernel(const float* __restrict__ in,
                                                 const float* __restrict__ w,
                                                 const float* __restrict__ b,
                                                 unsigned short* __restrict__ out) {
    int tid = threadIdx.x, lane = tid & 63, wid = tid >> 6;
    long r = (long)blockIdx.x * 4 + wid;
    long src;
    if (MODE == 0) {
        int n = (int)(r & 31); int win = (int)(r >> 5);
        int b_ = win >> 11, tw = (win >> 8) & 7, hw = (win >> 4) & 15, ww = win & 15;
        int ti = n >> 4, hi = (n >> 2) & 3, wi = n & 3;
        int t = tw * 2 + ti, hh = hw * 4 + hi, wv = ww * 4 + wi;
        int ts = (t + 1) & 15, hs = (hh + 2) & 63, wsd = (wv + 2) & 63;
        src = ((long)((b_ * 16 + ts) * 64 + hs)) * 64 + wsd;
    } else {
        src = r;
    }
    float4 v = *(const float4*)&in[src * CDIM + lane * 4];
    float vv[4] = {v.x, v.y, v.z, v.w};
    float s = vv[0] + vv[1] + vv[2] + vv[3];
    s = wave_sum(s);
    float mean = s * (1.0f / 256.0f);
    float q = vv[0]*vv[0] + vv[1]*vv[1] + vv[2]*vv[2] + vv[3]*vv[3];
    q = wave_sum(q);
    float var = q * (1.0f / 256.0f) - mean * mean;
    float rstd = rsqrtf(var + 1e-5f);
    int c0 = lane * 4;
    u16x4 o;
#pragma unroll
    for (int j = 0; j < 4; ++j)
        o[j] = f2bf((vv[j] - mean) * rstd * w[c0 + j] + b[c0 + j]);
    *(u16x4*)&out[r * CDIM + c0] = o;
}

// ---------- GEMM 256x256 tile, BK=64, 8 waves (2Mx4N), dbuf LDS, 1 barrier/K-tile ----
// EPI: 0 = bf16 store (stride NS)        1 = proj: window-reverse scatter + residual -> fp32
//      2 = GELU -> bf16 (stride NS)       3 = += into fp32 out (stride NS)
// Grid: flattened NX*512 blocks, bijective XCD swizzle, x = wg % NX (A-tile sharers adjacent)
template <int K, int EPI, int NS, int NX>
__global__ __launch_bounds__(512) void gemm256(const unsigned short* __restrict__ A,
                                               const unsigned short* __restrict__ Bt,
                                               const float* __restrict__ bias,
                                               float* __restrict__ outf,
                                               unsigned short* __restrict__ outb,
                                               const float* __restrict__ resid) {
    extern __shared__ unsigned short lds[];   // 65536 ushorts = 128 KiB
    const int tid = threadIdx.x;
    const int lane = tid & 63, wid = tid >> 6;
    const int wm = wid >> 2, wn = wid & 3;    // 2 x 4 waves, each owns 128x64 of C
    constexpr int NWG = NX * 512;
    constexpr int CPX = NWG / 8;
    const int bid = blockIdx.x;
    const int wg = (bid & 7) * CPX + (bid >> 3);
    const int n0 = (wg % NX) * 256;
    const size_t m0 = (size_t)(wg / NX) * 256;
    constexpr int NK = K / 64;

    fp32x4 acc[8][4] = {};

    auto stage = [&](int kt, int buf) {
#pragma unroll
        for (int i = 0; i < 4; ++i) {
            int L = i * 512 + tid;            // 0..2047 -> 256 rows x 8 chunks
            int r = L >> 3, c = L & 7;
            int sc = c ^ (r & 7);             // involution swizzle on global source
            const unsigned short* ga = A + (m0 + r) * K + kt * 64 + sc * 8;
            __builtin_amdgcn_global_load_lds(
                (const __attribute__((address_space(1))) void*)ga,
                (__attribute__((address_space(3))) void*)(lds + buf * 16384 + L * 8),
                16, 0, 0);
            const unsigned short* gb = Bt + (size_t)(n0 + r) * K + kt * 64 + sc * 8;
            __builtin_amdgcn_global_load_lds(
                (const __attribute__((address_space(1))) void*)gb,
                (__attribute__((address_space(3))) void*)(lds + 32768 + buf * 16384 + L * 8),
                16, 0, 0);
        }
    };

    stage(0, 0);
    __syncthreads();                          // implies vmcnt(0) drain
    for (int kt = 0; kt < NK; ++kt) {
        if (kt + 1 < NK) stage(kt + 1, (kt + 1) & 1);   // writes opposite buffer: race-free
        const unsigned short* As = lds + (kt & 1) * 16384;
        const unsigned short* Bs = lds + 32768 + (kt & 1) * 16384;
#pragma unroll
        for (int q = 0; q < 4; ++q) {         // 4 quadrant phases per K-tile
            const int qm = q >> 1, qn = q & 1;
            s16x8 a[4][2], b[2][2];
#pragma unroll
            for (int m = 0; m < 4; ++m)
#pragma unroll
                for (int ks = 0; ks < 2; ++ks) {
                    int row = wm * 128 + qm * 64 + m * 16 + (lane & 15);
                    int j = ks * 4 + (lane >> 4);
                    a[m][ks] = *(const s16x8*)(As + row * 64 + ((j ^ (row & 7)) << 3));
                }
#pragma unroll
            for (int n = 0; n < 2; ++n)
#pragma unroll
                for (int ks = 0; ks < 2; ++ks) {
                    int row = wn * 64 + qn * 32 + n * 16 + (lane & 15);
                    int j = ks * 4 + (lane >> 4);
                    b[n][ks] = *(const s16x8*)(Bs + row * 64 + ((j ^ (row & 7)) << 3));
                }
#pragma unroll
            for (int ks = 0; ks < 2; ++ks)
#pragma unroll
                for (int m = 0; m < 4; ++m)
#pragma unroll
                    for (int n = 0; n < 2; ++n)
                        acc[qm * 4 + m][qn * 2 + n] =
                            mfma16(a[m][ks], b[n][ks], acc[qm * 4 + m][qn * 2 + n]);
        }
        __syncthreads();                      // drains vmcnt: next buf landed
    }

    // epilogue
    float bv[4];
#pragma unroll
    for (int n = 0; n < 4; ++n) bv[n] = bias[n0 + wn * 64 + n * 16 + (lane & 15)];

#pragma unroll
    for (int m = 0; m < 8; ++m) {
#pragma unroll
        for (int rg = 0; rg < 4; ++rg) {
            int row_t = wm * 128 + m * 16 + ((lane >> 4) << 2) + rg;
            size_t gr = m0 + row_t;
            size_t dst = 0;
            if (EPI == 1) {
                int win = (int)(gr >> 5), n_ = (int)(gr & 31);
                int b_ = win >> 11, tw = (win >> 8) & 7, hw = (win >> 4) & 15, ww = win & 15;
                int ti = n_ >> 4, hi = (n_ >> 2) & 3, wi = n_ & 3;
                int t = tw * 2 + ti, hh = hw * 4 + hi, wv = ww * 4 + wi;
                int ts = (t + 1) & 15, hs = (hh + 2) & 63, wsd = (wv + 2) & 63;
                dst = ((size_t)((b_ * 16 + ts) * 64 + hs)) * 64 + wsd;
            }
#pragma unroll
            for (int n = 0; n < 4; ++n) {
                int gc = n0 + wn * 64 + n * 16 + (lane & 15);
                float v = acc[m][n][rg] + bv[n];
                if (EPI == 0) {
                    outb[gr * NS + gc] = f2bf(v);
                } else if (EPI == 1) {
                    outf[dst * CDIM + gc] = resid[dst * CDIM + gc] + v;
                } else if (EPI == 2) {
                    float g = 0.5f * v * (1.0f + erff(v * 0.70710678118654752f));
                    outb[gr * NS + gc] = f2bf(g);
                } else {
                    outf[gr * NS + gc] += v;
                }
            }
        }
    }
}

// ---------- windowed attention: one wave per (window, head) ----------
__global__ __launch_bounds__(256) void attn_kernel(const unsigned short* __restrict__ qkv,
                                                   const float* __restrict__ btab,
                                                   unsigned short* __restrict__ obuf) {
    __shared__ unsigned short sP[4][1280];    // 32 x 40 (pad) bf16 per wave
    __shared__ unsigned short sVt[4][1280];
    int tid = threadIdx.x, lane = tid & 63, wid = tid >> 6;
    int task = blockIdx.x * 4 + wid;          // 32768 tasks
    int win = task >> 3, hh = task & 7;
    const unsigned short* base = qkv + (size_t)win * 32 * 768 + hh * 32;
    int q = lane & 31, h = lane >> 5;

    // V -> LDS transposed (Vt[d][key])
    s16x8 v0 = *(const s16x8*)(base + 512 + q * 768 + h * 16);
    s16x8 v1 = *(const s16x8*)(base + 512 + q * 768 + h * 16 + 8);
#pragma unroll
    for (int j = 0; j < 8; ++j) {
        sVt[wid][(h * 16 + j) * 40 + q]     = (unsigned short)v0[j];
        sVt[wid][(h * 16 + 8 + j) * 40 + q] = (unsigned short)v1[j];
    }

    // S = Q K^T
    s16x8 aq0 = *(const s16x8*)(base + q * 768 + h * 8);
    s16x8 aq1 = *(const s16x8*)(base + q * 768 + 16 + h * 8);
    s16x8 bk0 = *(const s16x8*)(base + 256 + q * 768 + h * 8);
    s16x8 bk1 = *(const s16x8*)(base + 256 + q * 768 + 16 + h * 8);
    fp32x16 S = {0.0f};
    S = mfma32(aq0, bk0, S);
    S = mfma32(aq1, bk1, S);

    const float scale = 0.17677669529663687f;   // 1/sqrt(32)
    float pr[16];
#pragma unroll
    for (int r = 0; r < 16; ++r) {
        int row = (r & 3) + 8 * (r >> 2) + 4 * h;
        float bvv = btab[(hh * 32 + row) * 32 + q];
        pr[r] = S[r] * scale + bvv;
    }
#pragma unroll
    for (int r = 0; r < 16; ++r) {
        float mx = pr[r];
#pragma unroll
        for (int off = 16; off > 0; off >>= 1) mx = fmaxf(mx, __shfl_xor(mx, off, 64));
        float e = __expf(pr[r] - mx);
        float sm = e;
#pragma unroll
        for (int off = 16; off > 0; off >>= 1) sm += __shfl_xor(sm, off, 64);
        pr[r] = e * __builtin_amdgcn_rcpf(sm);
    }
#pragma unroll
    for (int r = 0; r < 16; ++r) {
        int row = (r & 3) + 8 * (r >> 2) + 4 * h;
        sP[wid][row * 40 + q] = f2bf(pr[r]);
    }
    __syncthreads();

    // O = P V
    s16x8 pa0 = *(const s16x8*)&sP[wid][q * 40 + h * 8];
    s16x8 pa1 = *(const s16x8*)&sP[wid][q * 40 + 16 + h * 8];
    s16x8 vb0 = *(const s16x8*)&sVt[wid][q * 40 + h * 8];
    s16x8 vb1 = *(const s16x8*)&sVt[wid][q * 40 + 16 + h * 8];
    fp32x16 O = {0.0f};
    O = mfma32(pa0, vb0, O);
    O = mfma32(pa1, vb1, O);
#pragma unroll
    for (int r = 0; r < 16; ++r) {
        int row = (r & 3) + 8 * (r >> 2) + 4 * h;
        obuf[((size_t)win * 32 + row) * 256 + hh * 32 + q] = f2bf(O[r]);
    }
}

// ---------- launcher ----------
extern "C" void kernel_launch(void* const* d_in, const int* in_sizes, int n_in,
                              void* d_out, int out_size, void* d_ws, size_t ws_size,
                              hipStream_t stream) {
    const float* x      = (const float*)d_in[0];
    const float* n1w    = (const float*)d_in[1];
    const float* n1b    = (const float*)d_in[2];
    const float* qkv_w  = (const float*)d_in[3];
    const float* qkv_b  = (const float*)d_in[4];
    const float* proj_w = (const float*)d_in[5];
    const float* proj_b = (const float*)d_in[6];
    const float* rel    = (const float*)d_in[7];
    const float* n2w    = (const float*)d_in[8];
    const float* n2b    = (const float*)d_in[9];
    const float* w1     = (const float*)d_in[10];
    const float* b1     = (const float*)d_in[11];
    const float* w2     = (const float*)d_in[12];
    const float* b2     = (const float*)d_in[13];
    float* out = (float*)d_out;

    char* ws = (char*)d_ws;
    unsigned short* hwin = (unsigned short*)ws;                       // 67,108,864 B
    unsigned short* big  = (unsigned short*)(ws + 67108864);          // 268,435,456 B
    char* wreg = ws + 67108864 + 268435456;
    unsigned short* qkvT  = (unsigned short*)(wreg);
    unsigned short* projT = (unsigned short*)(wreg + 393216);
    unsigned short* w1T   = (unsigned short*)(wreg + 524288);
    unsigned short* w2T   = (unsigned short*)(wreg + 1048576);
    float*          btab  = (float*)(wreg + 1572864);

    prep_kernel<<<3104, 256, 0, stream>>>(qkv_w, proj_w, w1, w2, rel, qkvT, projT, w1T, w2T, btab);

    ln_kernel<0><<<NTOK / 4, 256, 0, stream>>>(x, n1w, n1b, hwin);

    // qkv = hwin @ qkvT^T + qkv_b -> bf16 [NTOK][768]
    gemm256<256, 0, 768, 3><<<1536, 512, 131072, stream>>>(hwin, qkvT, qkv_b, nullptr, big, nullptr);

    attn_kernel<<<8192, 256, 0, stream>>>(big, btab, hwin);           // obuf -> hwin region

    // proj + window-reverse + roll + residual -> d_out (x2)
    gemm256<256, 1, 256, 1><<<512, 512, 131072, stream>>>(hwin, projT, proj_b, out, nullptr, x);

    ln_kernel<1><<<NTOK / 4, 256, 0, stream>>>(out, n2w, n2b, hwin);  // a2 -> hwin region

    // hidden = gelu(a2 @ w1T^T + b1) -> bf16 [NTOK][1024]
    gemm256<256, 2, 1024, 4><<<2048, 512, 131072, stream>>>(hwin, w1T, b1, nullptr, big, nullptr);

    // d_out += hidden @ w2T^T + b2
    gemm256<1024, 3, 256, 1><<<512, 512, 131072, stream>>>(big, w2T, b2, out, nullptr, nullptr);
}